// Round 2
// baseline (2894.466 us; speedup 1.0000x reference)
//
#include <hip/hip_runtime.h>
#include <hip/hip_bf16.h>
#include <cstdint>

#define BATCH  4
#define SEQ    2048
#define DMODEL 1024
#define DFF    4096
#define MTOT   (BATCH * SEQ)   // 8192
#define KCONV  5
#define PADC   2

#define BM 128
#define BN 128
#define BK 8

using bf16raw = unsigned short;

__device__ __forceinline__ float bf2f(bf16raw u) {
    return __uint_as_float(((uint32_t)u) << 16);
}
__device__ __forceinline__ bf16raw f2bf(float f) {
    uint32_t u = __float_as_uint(f);
    u = (u + 0x7fffu + ((u >> 16) & 1u)) >> 16;   // round-to-nearest-even
    return (bf16raw)u;
}

__device__ __forceinline__ void load4(const float* p, float v[4]) {
    const float4 t = *reinterpret_cast<const float4*>(p);
    v[0] = t.x; v[1] = t.y; v[2] = t.z; v[3] = t.w;
}
__device__ __forceinline__ void load4(const bf16raw* p, float v[4]) {
    const ushort4 t = *reinterpret_cast<const ushort4*>(p);
    v[0] = bf2f(t.x); v[1] = bf2f(t.y); v[2] = bf2f(t.z); v[3] = bf2f(t.w);
}
__device__ __forceinline__ void store4(float* p, const float v[4]) {
    float4 t; t.x = v[0]; t.y = v[1]; t.z = v[2]; t.w = v[3];
    *reinterpret_cast<float4*>(p) = t;
}
__device__ __forceinline__ void store4(bf16raw* p, const float v[4]) {
    ushort4 t; t.x = f2bf(v[0]); t.y = f2bf(v[1]); t.z = f2bf(v[2]); t.w = f2bf(v[3]);
    *reinterpret_cast<ushort4*>(p) = t;
}

// C[M,N] = A[M,K] @ B[K,N] + bias[N]; row-major; M,N %128==0, K%8==0
template<typename AT, typename CT>
__global__ __launch_bounds__(256)
void sgemm_bias_kernel(const AT* __restrict__ A, const float* __restrict__ B,
                       const float* __restrict__ bias, CT* __restrict__ C,
                       int N, int K)
{
    __shared__ float As[BK][BM];
    __shared__ float Bs[BK][BN];

    const int tid = threadIdx.x;
    const int bm  = blockIdx.y * BM;
    const int bn  = blockIdx.x * BN;
    const int tx  = tid & 15;    // n-group 0..15
    const int ty  = tid >> 4;    // m-group 0..15

    const int arow = tid >> 1;          // 0..127
    const int acol = (tid & 1) * 4;     // 0 or 4
    const int brow = tid >> 5;          // 0..7
    const int bcol = (tid & 31) * 4;    // 0..124

    const AT*    Ap = A + (size_t)(bm + arow) * K + acol;
    const float* Bp = B + (size_t)brow * N + bn + bcol;

    float acc[8][8];
#pragma unroll
    for (int i = 0; i < 8; ++i)
#pragma unroll
        for (int j = 0; j < 8; ++j) acc[i][j] = 0.f;

    for (int k0 = 0; k0 < K; k0 += BK) {
        float av[4];
        load4(Ap + k0, av);
        const float4 bv = *reinterpret_cast<const float4*>(Bp + (size_t)k0 * N);

        __syncthreads();
#pragma unroll
        for (int i = 0; i < 4; ++i) As[acol + i][arow] = av[i];
        *reinterpret_cast<float4*>(&Bs[brow][bcol]) = bv;
        __syncthreads();

#pragma unroll
        for (int kk = 0; kk < BK; ++kk) {
            const float4 a0 = *reinterpret_cast<const float4*>(&As[kk][ty * 4]);
            const float4 a1 = *reinterpret_cast<const float4*>(&As[kk][64 + ty * 4]);
            const float4 b0 = *reinterpret_cast<const float4*>(&Bs[kk][tx * 4]);
            const float4 b1 = *reinterpret_cast<const float4*>(&Bs[kk][64 + tx * 4]);
            const float am[8] = {a0.x, a0.y, a0.z, a0.w, a1.x, a1.y, a1.z, a1.w};
            const float bb[8] = {b0.x, b0.y, b0.z, b0.w, b1.x, b1.y, b1.z, b1.w};
#pragma unroll
            for (int mi = 0; mi < 8; ++mi)
#pragma unroll
                for (int nj = 0; nj < 8; ++nj)
                    acc[mi][nj] += am[mi] * bb[nj];
        }
    }

#pragma unroll
    for (int mi = 0; mi < 8; ++mi) {
        const int m = bm + ((mi < 4) ? (ty * 4 + mi) : (64 + ty * 4 + (mi - 4)));
#pragma unroll
        for (int g = 0; g < 2; ++g) {
            const int n = bn + g * 64 + tx * 4;
            float o[4];
#pragma unroll
            for (int c = 0; c < 4; ++c) o[c] = acc[mi][g * 4 + c] + bias[n + c];
            store4(&C[(size_t)m * N + n], o);
        }
    }
}

// One batch chunk (SEQ rows): h = silu(dwconv(gp)) * dwconv(up)
// One thread per (row, 4 consecutive channels).
template<typename PT, typename HT>
__global__ __launch_bounds__(256)
void conv_silu_mul_kernel(const PT* __restrict__ gp, const PT* __restrict__ up,
                          const float* __restrict__ wg, const float* __restrict__ cbg,
                          const float* __restrict__ wu, const float* __restrict__ cbu,
                          HT* __restrict__ hout)
{
    const int idx = blockIdx.x * 256 + threadIdx.x;
    const int f   = (idx & (DFF / 4 - 1)) * 4;
    const int l   = idx >> 10;                  // row within batch: 0..SEQ-1

    float g[4], u[4];
    load4(cbg + f, g);
    load4(cbu + f, u);

#pragma unroll
    for (int j = 0; j < KCONV; ++j) {
        const int ls = l + j - PADC;
        if (ls < 0 || ls >= SEQ) continue;      // per-batch zero padding
        const size_t off = (size_t)ls * DFF + f;
        float gv[4], uv[4];
        load4(gp + off, gv);
        load4(up + off, uv);
#pragma unroll
        for (int c = 0; c < 4; ++c) {
            g[c] += gv[c] * wg[(f + c) * KCONV + j];
            u[c] += uv[c] * wu[(f + c) * KCONV + j];
        }
    }

    float h[4];
#pragma unroll
    for (int c = 0; c < 4; ++c) {
        const float s = g[c] / (1.f + __expf(-g[c]));
        h[c] = s * u[c];
    }
    store4(hout + (size_t)l * DFF + f, h);
}

extern "C" void kernel_launch(void* const* d_in, const int* in_sizes, int n_in,
                              void* d_out, int out_size, void* d_ws, size_t ws_size,
                              hipStream_t stream)
{
    const float* x   = (const float*)d_in[0];
    const float* Wg  = (const float*)d_in[1];
    const float* bg  = (const float*)d_in[2];
    const float* Wu  = (const float*)d_in[3];
    const float* bu  = (const float*)d_in[4];
    const float* cgw = (const float*)d_in[5];
    const float* cgb = (const float*)d_in[6];
    const float* cuw = (const float*)d_in[7];
    const float* cub = (const float*)d_in[8];
    const float* Wd  = (const float*)d_in[9];
    const float* bd  = (const float*)d_in[10];
    float* out = (float*)d_out;

    const size_t CE  = (size_t)SEQ * DFF;          // elements per chunk buffer
    const size_t P32 = CE * sizeof(float);         // 32 MiB
    const size_t P16 = CE * sizeof(bf16raw);       // 16 MiB

    dim3 blk(256);
    dim3 gu(DFF / BN, SEQ / BM);       // 32 x 16  (per-chunk up-GEMM)
    dim3 gdc(DMODEL / BN, SEQ / BM);   //  8 x 16  (per-chunk down-GEMM)
    const int nconv = SEQ * (DFF / 4) / 256;   // 8192 blocks

    if (ws_size >= 6 * P32) {
        // Path A: full fp32 h (128 MiB) + rotating fp32 pre-buffers (64 MiB)
        float* hfull = (float*)d_ws;
        float* gpre  = (float*)((char*)d_ws + 4 * P32);
        float* upre  = gpre + CE;
        for (int b = 0; b < BATCH; ++b) {
            const float* xb = x + (size_t)b * SEQ * DMODEL;
            sgemm_bias_kernel<float, float><<<gu, blk, 0, stream>>>(xb, Wg, bg, gpre, DFF, DMODEL);
            sgemm_bias_kernel<float, float><<<gu, blk, 0, stream>>>(xb, Wu, bu, upre, DFF, DMODEL);
            conv_silu_mul_kernel<float, float><<<nconv, blk, 0, stream>>>(
                gpre, upre, cgw, cgb, cuw, cub, hfull + (size_t)b * CE);
        }
        dim3 gdf(DMODEL / BN, MTOT / BM);  // 8 x 64
        sgemm_bias_kernel<float, float><<<gdf, blk, 0, stream>>>(hfull, Wd, bd, out, DMODEL, DFF);
    } else if (ws_size >= 3 * P32) {
        // Path B: fully per-batch, fp32 intermediates (96 MiB)
        float* gpre = (float*)d_ws;
        float* upre = gpre + CE;
        float* hbuf = upre + CE;
        for (int b = 0; b < BATCH; ++b) {
            const float* xb = x + (size_t)b * SEQ * DMODEL;
            float* outb = out + (size_t)b * SEQ * DMODEL;
            sgemm_bias_kernel<float, float><<<gu, blk, 0, stream>>>(xb, Wg, bg, gpre, DFF, DMODEL);
            sgemm_bias_kernel<float, float><<<gu, blk, 0, stream>>>(xb, Wu, bu, upre, DFF, DMODEL);
            conv_silu_mul_kernel<float, float><<<nconv, blk, 0, stream>>>(
                gpre, upre, cgw, cgb, cuw, cub, hbuf);
            sgemm_bias_kernel<float, float><<<gdc, blk, 0, stream>>>(hbuf, Wd, bd, outb, DMODEL, DFF);
        }
    } else if (ws_size >= 3 * P16) {
        // Path C: fully per-batch, bf16 intermediates (48 MiB)
        bf16raw* gpre = (bf16raw*)d_ws;
        bf16raw* upre = gpre + CE;
        bf16raw* hbuf = upre + CE;
        for (int b = 0; b < BATCH; ++b) {
            const float* xb = x + (size_t)b * SEQ * DMODEL;
            float* outb = out + (size_t)b * SEQ * DMODEL;
            sgemm_bias_kernel<float, bf16raw><<<gu, blk, 0, stream>>>(xb, Wg, bg, gpre, DFF, DMODEL);
            sgemm_bias_kernel<float, bf16raw><<<gu, blk, 0, stream>>>(xb, Wu, bu, upre, DFF, DMODEL);
            conv_silu_mul_kernel<bf16raw, bf16raw><<<nconv, blk, 0, stream>>>(
                gpre, upre, cgw, cgb, cuw, cub, hbuf);
            sgemm_bias_kernel<bf16raw, float><<<gdc, blk, 0, stream>>>(hbuf, Wd, bd, outb, DMODEL, DFF);
        }
    }
    // ws < 48 MiB: launch nothing -> clean absmax failure as ws-size diagnostic
}

// Round 3
// 441.459 us; speedup vs baseline: 6.5566x; 6.5566x over previous
//
#include <hip/hip_runtime.h>
#include <hip/hip_bf16.h>
#include <cstdint>

#define BATCH  4
#define SEQ    2048
#define DMODEL 1024
#define DFF    4096
#define MTOT   (BATCH * SEQ)   // 8192
#define KCONV  5
#define PADC   2

using bf16raw = unsigned short;
typedef __attribute__((ext_vector_type(8))) short bf16x8;
typedef __attribute__((ext_vector_type(4))) float f32x4;

__device__ __forceinline__ float bf2f(bf16raw u) {
    return __uint_as_float(((uint32_t)u) << 16);
}
__device__ __forceinline__ bf16raw f2bf(float f) {
    uint32_t u = __float_as_uint(f);
    u = (u + 0x7fffu + ((u >> 16) & 1u)) >> 16;   // RNE
    return (bf16raw)u;
}

// ---------------- prep kernels ----------------

__global__ __launch_bounds__(256)
void cvt_bf16_kernel(const float* __restrict__ in, bf16raw* __restrict__ out, int n4)
{
    const int i = blockIdx.x * 256 + threadIdx.x;
    if (i >= n4) return;
    const float4 v = reinterpret_cast<const float4*>(in)[i];
    ushort4 o;
    o.x = f2bf(v.x); o.y = f2bf(v.y); o.z = f2bf(v.z); o.w = f2bf(v.w);
    reinterpret_cast<ushort4*>(out)[i] = o;
}

// out[C][R] = bf16(in[R][C]); R,C multiples of 32
__global__ __launch_bounds__(256)
void transpose_cvt_kernel(const float* __restrict__ in, bf16raw* __restrict__ out,
                          int R, int C)
{
    __shared__ float tile[32][33];
    const int r0 = blockIdx.y * 32, c0 = blockIdx.x * 32;
    const int tx = threadIdx.x & 31, ty = threadIdx.x >> 5;  // ty 0..7
#pragma unroll
    for (int i = 0; i < 4; ++i)
        tile[ty + i * 8][tx] = in[(size_t)(r0 + ty + i * 8) * C + c0 + tx];
    __syncthreads();
#pragma unroll
    for (int i = 0; i < 4; ++i)
        out[(size_t)(c0 + ty + i * 8) * R + r0 + tx] = f2bf(tile[tx][ty + i * 8]);
}

// conv weights [DFF][1][K] -> [K][DFF] fp32
__global__ __launch_bounds__(256)
void convw_reorder_kernel(const float* __restrict__ wg, const float* __restrict__ wu,
                          float* __restrict__ wgT, float* __restrict__ wuT)
{
    const int i = blockIdx.x * 256 + threadIdx.x;
    if (i >= KCONV * DFF) return;
    const int j = i / DFF, f = i - j * DFF;
    wgT[i] = wg[f * KCONV + j];
    wuT[i] = wu[f * KCONV + j];
}

// ---------------- MFMA GEMM ----------------
// C[M][N] = A[M][K] @ BT[N][K]^T + bias; M,N %128==0, K %64==0
// m97 structure: 128x128 tile, BK=64, 4 waves (2x2), global_load_lds width 16.

__device__ __forceinline__ void async_load16(const bf16raw* g, bf16raw* lds)
{
    __builtin_amdgcn_global_load_lds(
        (const __attribute__((address_space(1))) void*)g,
        (__attribute__((address_space(3))) void*)lds, 16, 0, 0);
}

template<typename CT>
__global__ __launch_bounds__(256)
void mfma_gemm_kernel(const bf16raw* __restrict__ A, const bf16raw* __restrict__ BT,
                      const float* __restrict__ bias, CT* __restrict__ C,
                      int N, int K)
{
    __shared__ __align__(16) bf16raw smem[2 * 128 * 64];
    bf16raw* As = smem;             // [128][64]
    bf16raw* Bs = smem + 128 * 64;  // [128][64]

    const int tid  = threadIdx.x;
    const int lane = tid & 63;
    const int wave = __builtin_amdgcn_readfirstlane(tid >> 6);
    const int bm = blockIdx.y * 128;
    const int bn = blockIdx.x * 128;
    const int wm = (wave >> 1) * 64;
    const int wn = (wave & 1) * 64;

    // staging geometry: per round r (0..3), wave covers rows r*32 + wave*8 + lane/8
    const int srow = (wave << 3) + (lane >> 3);
    const int scol = (lane & 7) << 3;
    const bf16raw* Ag = A  + (size_t)(bm + srow) * K + scol;
    const bf16raw* Bg = BT + (size_t)(bn + srow) * K + scol;

    f32x4 acc[4][4];
#pragma unroll
    for (int i = 0; i < 4; ++i)
#pragma unroll
        for (int j = 0; j < 4; ++j) acc[i][j] = (f32x4){0.f, 0.f, 0.f, 0.f};

    for (int k0 = 0; k0 < K; k0 += 64) {
        __syncthreads();   // prior compute done reading LDS
#pragma unroll
        for (int r = 0; r < 4; ++r) {
            async_load16(Ag + (size_t)(r * 32) * K + k0, As + r * 2048 + wave * 512);
            async_load16(Bg + (size_t)(r * 32) * K + k0, Bs + r * 2048 + wave * 512);
        }
        asm volatile("s_waitcnt vmcnt(0)" ::: "memory");
        __syncthreads();

#pragma unroll
        for (int kk = 0; kk < 2; ++kk) {
            const int kb = kk * 32 + ((lane >> 4) << 3);
            bf16x8 a[4], b[4];
#pragma unroll
            for (int i = 0; i < 4; ++i) {
                a[i] = *reinterpret_cast<const bf16x8*>(As + (wm + i * 16 + (lane & 15)) * 64 + kb);
                b[i] = *reinterpret_cast<const bf16x8*>(Bs + (wn + i * 16 + (lane & 15)) * 64 + kb);
            }
#pragma unroll
            for (int mi = 0; mi < 4; ++mi)
#pragma unroll
                for (int ni = 0; ni < 4; ++ni)
                    acc[mi][ni] = __builtin_amdgcn_mfma_f32_16x16x32_bf16(
                        a[mi], b[ni], acc[mi][ni], 0, 0, 0);
        }
    }

    // epilogue: C/D layout col=lane&15, row=(lane>>4)*4+reg  [m89]
    const int crow0 = (lane >> 4) << 2;
    const int ccol  = lane & 15;
#pragma unroll
    for (int ni = 0; ni < 4; ++ni) {
        const int n = bn + wn + ni * 16 + ccol;
        const float bs = bias[n];
#pragma unroll
        for (int mi = 0; mi < 4; ++mi) {
            const int mbase = bm + wm + mi * 16 + crow0;
#pragma unroll
            for (int j = 0; j < 4; ++j) {
                const float v = acc[mi][ni][j] + bs;
                if constexpr (sizeof(CT) == 2)
                    C[(size_t)(mbase + j) * N + n] = f2bf(v);
                else
                    C[(size_t)(mbase + j) * N + n] = v;
            }
        }
    }
}

// ---------------- conv + silu + mul (bf16 in/out) ----------------
// one thread per (row, 8 channels); rows may span batches (l = row & (SEQ-1))
__global__ __launch_bounds__(256)
void conv_silu_mul_bf16_kernel(const bf16raw* __restrict__ gp, const bf16raw* __restrict__ up,
                               const float* __restrict__ wgT, const float* __restrict__ cbg,
                               const float* __restrict__ wuT, const float* __restrict__ cbu,
                               bf16raw* __restrict__ h, int rows)
{
    const int idx = blockIdx.x * 256 + threadIdx.x;
    const int f   = (idx & (DFF / 8 - 1)) << 3;
    const int row = idx >> 9;
    if (row >= rows) return;
    const int l = row & (SEQ - 1);

    float g[8], u[8];
    {
        const float4 a0 = *reinterpret_cast<const float4*>(cbg + f);
        const float4 a1 = *reinterpret_cast<const float4*>(cbg + f + 4);
        const float4 b0 = *reinterpret_cast<const float4*>(cbu + f);
        const float4 b1 = *reinterpret_cast<const float4*>(cbu + f + 4);
        g[0]=a0.x; g[1]=a0.y; g[2]=a0.z; g[3]=a0.w; g[4]=a1.x; g[5]=a1.y; g[6]=a1.z; g[7]=a1.w;
        u[0]=b0.x; u[1]=b0.y; u[2]=b0.z; u[3]=b0.w; u[4]=b1.x; u[5]=b1.y; u[6]=b1.z; u[7]=b1.w;
    }

#pragma unroll
    for (int j = 0; j < KCONV; ++j) {
        const int ls = l + j - PADC;
        if (ls < 0 || ls >= SEQ) continue;          // per-batch zero padding
        const size_t off = (size_t)(row + j - PADC) * DFF + f;
        const bf16x8 gv = *reinterpret_cast<const bf16x8*>(gp + off);
        const bf16x8 uv = *reinterpret_cast<const bf16x8*>(up + off);
        const float4 wa0 = *reinterpret_cast<const float4*>(wgT + j * DFF + f);
        const float4 wa1 = *reinterpret_cast<const float4*>(wgT + j * DFF + f + 4);
        const float4 wb0 = *reinterpret_cast<const float4*>(wuT + j * DFF + f);
        const float4 wb1 = *reinterpret_cast<const float4*>(wuT + j * DFF + f + 4);
        const float wg8[8] = {wa0.x, wa0.y, wa0.z, wa0.w, wa1.x, wa1.y, wa1.z, wa1.w};
        const float wu8[8] = {wb0.x, wb0.y, wb0.z, wb0.w, wb1.x, wb1.y, wb1.z, wb1.w};
#pragma unroll
        for (int c = 0; c < 8; ++c) {
            g[c] += bf2f((bf16raw)gv[c]) * wg8[c];
            u[c] += bf2f((bf16raw)uv[c]) * wu8[c];
        }
    }

    bf16x8 hv;
#pragma unroll
    for (int c = 0; c < 8; ++c) {
        const float s = g[c] / (1.f + __expf(-g[c]));
        hv[c] = (short)f2bf(s * u[c]);
    }
    *reinterpret_cast<bf16x8*>(h + (size_t)row * DFF + f) = hv;
}

// ---------------- fp32 fallback kernels (round-2, proven) ----------------

#define BM 128
#define BN 128
#define BK 8

__device__ __forceinline__ void load4(const float* p, float v[4]) {
    const float4 t = *reinterpret_cast<const float4*>(p);
    v[0] = t.x; v[1] = t.y; v[2] = t.z; v[3] = t.w;
}
__device__ __forceinline__ void load4(const bf16raw* p, float v[4]) {
    const ushort4 t = *reinterpret_cast<const ushort4*>(p);
    v[0] = bf2f(t.x); v[1] = bf2f(t.y); v[2] = bf2f(t.z); v[3] = bf2f(t.w);
}
__device__ __forceinline__ void store4(float* p, const float v[4]) {
    float4 t; t.x = v[0]; t.y = v[1]; t.z = v[2]; t.w = v[3];
    *reinterpret_cast<float4*>(p) = t;
}
__device__ __forceinline__ void store4(bf16raw* p, const float v[4]) {
    ushort4 t; t.x = f2bf(v[0]); t.y = f2bf(v[1]); t.z = f2bf(v[2]); t.w = f2bf(v[3]);
    *reinterpret_cast<ushort4*>(p) = t;
}

template<typename AT, typename CT>
__global__ __launch_bounds__(256)
void sgemm_bias_kernel(const AT* __restrict__ A, const float* __restrict__ B,
                       const float* __restrict__ bias, CT* __restrict__ C,
                       int N, int K)
{
    __shared__ float As[BK][BM];
    __shared__ float Bs[BK][BN];

    const int tid = threadIdx.x;
    const int bm  = blockIdx.y * BM;
    const int bn  = blockIdx.x * BN;
    const int tx  = tid & 15;
    const int ty  = tid >> 4;

    const int arow = tid >> 1;
    const int acol = (tid & 1) * 4;
    const int brow = tid >> 5;
    const int bcol = (tid & 31) * 4;

    const AT*    Ap = A + (size_t)(bm + arow) * K + acol;
    const float* Bp = B + (size_t)brow * N + bn + bcol;

    float acc[8][8];
#pragma unroll
    for (int i = 0; i < 8; ++i)
#pragma unroll
        for (int j = 0; j < 8; ++j) acc[i][j] = 0.f;

    for (int k0 = 0; k0 < K; k0 += BK) {
        float av[4];
        load4(Ap + k0, av);
        const float4 bv = *reinterpret_cast<const float4*>(Bp + (size_t)k0 * N);

        __syncthreads();
#pragma unroll
        for (int i = 0; i < 4; ++i) As[acol + i][arow] = av[i];
        *reinterpret_cast<float4*>(&Bs[brow][bcol]) = bv;
        __syncthreads();

#pragma unroll
        for (int kk = 0; kk < BK; ++kk) {
            const float4 a0 = *reinterpret_cast<const float4*>(&As[kk][ty * 4]);
            const float4 a1 = *reinterpret_cast<const float4*>(&As[kk][64 + ty * 4]);
            const float4 b0 = *reinterpret_cast<const float4*>(&Bs[kk][tx * 4]);
            const float4 b1 = *reinterpret_cast<const float4*>(&Bs[kk][64 + tx * 4]);
            const float am[8] = {a0.x, a0.y, a0.z, a0.w, a1.x, a1.y, a1.z, a1.w};
            const float bb[8] = {b0.x, b0.y, b0.z, b0.w, b1.x, b1.y, b1.z, b1.w};
#pragma unroll
            for (int mi = 0; mi < 8; ++mi)
#pragma unroll
                for (int nj = 0; nj < 8; ++nj)
                    acc[mi][nj] += am[mi] * bb[nj];
        }
    }

#pragma unroll
    for (int mi = 0; mi < 8; ++mi) {
        const int m = bm + ((mi < 4) ? (ty * 4 + mi) : (64 + ty * 4 + (mi - 4)));
#pragma unroll
        for (int g = 0; g < 2; ++g) {
            const int n = bn + g * 64 + tx * 4;
            float o[4];
#pragma unroll
            for (int c = 0; c < 4; ++c) o[c] = acc[mi][g * 4 + c] + bias[n + c];
            store4(&C[(size_t)m * N + n], o);
        }
    }
}

template<typename PT, typename HT>
__global__ __launch_bounds__(256)
void conv_silu_mul_kernel(const PT* __restrict__ gp, const PT* __restrict__ up,
                          const float* __restrict__ wg, const float* __restrict__ cbg,
                          const float* __restrict__ wu, const float* __restrict__ cbu,
                          HT* __restrict__ hout)
{
    const int idx = blockIdx.x * 256 + threadIdx.x;
    const int f   = (idx & (DFF / 4 - 1)) * 4;
    const int l   = idx >> 10;

    float g[4], u[4];
    load4(cbg + f, g);
    load4(cbu + f, u);

#pragma unroll
    for (int j = 0; j < KCONV; ++j) {
        const int ls = l + j - PADC;
        if (ls < 0 || ls >= SEQ) continue;
        const size_t off = (size_t)ls * DFF + f;
        float gv[4], uv[4];
        load4(gp + off, gv);
        load4(up + off, uv);
#pragma unroll
        for (int c = 0; c < 4; ++c) {
            g[c] += gv[c] * wg[(f + c) * KCONV + j];
            u[c] += uv[c] * wu[(f + c) * KCONV + j];
        }
    }

    float h[4];
#pragma unroll
    for (int c = 0; c < 4; ++c) {
        const float s = g[c] / (1.f + __expf(-g[c]));
        h[c] = s * u[c];
    }
    store4(hout + (size_t)l * DFF + f, h);
}

// ---------------- launch ----------------

extern "C" void kernel_launch(void* const* d_in, const int* in_sizes, int n_in,
                              void* d_out, int out_size, void* d_ws, size_t ws_size,
                              hipStream_t stream)
{
    const float* x   = (const float*)d_in[0];
    const float* Wg  = (const float*)d_in[1];
    const float* bg  = (const float*)d_in[2];
    const float* Wu  = (const float*)d_in[3];
    const float* bu  = (const float*)d_in[4];
    const float* cgw = (const float*)d_in[5];
    const float* cgb = (const float*)d_in[6];
    const float* cuw = (const float*)d_in[7];
    const float* cub = (const float*)d_in[8];
    const float* Wd  = (const float*)d_in[9];
    const float* bd  = (const float*)d_in[10];
    float* out = (float*)d_out;

    const dim3 blk(256);

    // byte sizes
    const size_t SZ_XB  = (size_t)MTOT * DMODEL * 2;   // 16 MiB
    const size_t SZ_W   = (size_t)DFF * DMODEL * 2;    //  8 MiB each
    const size_t SZ_CW  = (size_t)KCONV * DFF * 4;     // 80 KiB each
    const size_t SZ_PF  = (size_t)MTOT * DFF * 2;      // 64 MiB (full pre/h)
    const size_t SZ_PB  = (size_t)SEQ  * DFF * 2;      // 16 MiB (per-batch pre)

    auto align256 = [](size_t v) { return (v + 255) & ~(size_t)255; };

    // common prefix layout for MFMA tiers
    size_t cur = 0;
    const size_t oXB  = cur; cur = align256(cur + SZ_XB);
    const size_t oWgT = cur; cur = align256(cur + SZ_W);
    const size_t oWuT = cur; cur = align256(cur + SZ_W);
    const size_t oWdT = cur; cur = align256(cur + SZ_W);
    const size_t oCWg = cur; cur = align256(cur + SZ_CW);
    const size_t oCWu = cur; cur = align256(cur + SZ_CW);
    const size_t oH   = cur; cur = align256(cur + SZ_PF);
    const size_t oPRE = cur;   // gpre/upre region
    const size_t needT1 = oPRE + 2 * align256(SZ_PF);
    const size_t needT2 = oPRE + 2 * align256(SZ_PB);

    if (ws_size >= needT2) {
        bf16raw* xb  = (bf16raw*)((char*)d_ws + oXB);
        bf16raw* WgT = (bf16raw*)((char*)d_ws + oWgT);
        bf16raw* WuT = (bf16raw*)((char*)d_ws + oWuT);
        bf16raw* WdT = (bf16raw*)((char*)d_ws + oWdT);
        float*   cwg = (float*)((char*)d_ws + oCWg);
        float*   cwu = (float*)((char*)d_ws + oCWu);
        bf16raw* h   = (bf16raw*)((char*)d_ws + oH);

        // prep
        cvt_bf16_kernel<<<(MTOT * DMODEL / 4 + 255) / 256, blk, 0, stream>>>(x, xb, MTOT * DMODEL / 4);
        transpose_cvt_kernel<<<dim3(DFF / 32, DMODEL / 32), blk, 0, stream>>>(Wg, WgT, DMODEL, DFF);
        transpose_cvt_kernel<<<dim3(DFF / 32, DMODEL / 32), blk, 0, stream>>>(Wu, WuT, DMODEL, DFF);
        transpose_cvt_kernel<<<dim3(DMODEL / 32, DFF / 32), blk, 0, stream>>>(Wd, WdT, DFF, DMODEL);
        convw_reorder_kernel<<<(KCONV * DFF + 255) / 256, blk, 0, stream>>>(cgw, cuw, cwg, cwu);

        if (ws_size >= needT1) {
            // tier 1: full-M up-GEMMs
            bf16raw* gpre = (bf16raw*)((char*)d_ws + oPRE);
            bf16raw* upre = (bf16raw*)((char*)d_ws + oPRE + align256(SZ_PF));
            dim3 gu(DFF / 128, MTOT / 128);    // 32 x 64
            mfma_gemm_kernel<bf16raw><<<gu, blk, 0, stream>>>(xb, WgT, bg, gpre, DFF, DMODEL);
            mfma_gemm_kernel<bf16raw><<<gu, blk, 0, stream>>>(xb, WuT, bu, upre, DFF, DMODEL);
            const int nconv = MTOT * (DFF / 8) / 256;
            conv_silu_mul_bf16_kernel<<<nconv, blk, 0, stream>>>(gpre, upre, cwg, cgb, cwu, cub, h, MTOT);
        } else {
            // tier 2: per-batch up-GEMMs into rotating buffers
            bf16raw* gpre = (bf16raw*)((char*)d_ws + oPRE);
            bf16raw* upre = (bf16raw*)((char*)d_ws + oPRE + align256(SZ_PB));
            dim3 gu(DFF / 128, SEQ / 128);     // 32 x 16
            const int nconv = SEQ * (DFF / 8) / 256;
            for (int b = 0; b < BATCH; ++b) {
                const bf16raw* xbb = xb + (size_t)b * SEQ * DMODEL;
                mfma_gemm_kernel<bf16raw><<<gu, blk, 0, stream>>>(xbb, WgT, bg, gpre, DFF, DMODEL);
                mfma_gemm_kernel<bf16raw><<<gu, blk, 0, stream>>>(xbb, WuT, bu, upre, DFF, DMODEL);
                conv_silu_mul_bf16_kernel<<<nconv, blk, 0, stream>>>(
                    gpre, upre, cwg, cgb, cwu, cub, h + (size_t)b * SEQ * DFF, SEQ);
            }
        }
        // down-GEMM over full M
        dim3 gd(DMODEL / 128, MTOT / 128);     // 8 x 64
        mfma_gemm_kernel<float><<<gd, blk, 0, stream>>>(h, WdT, bd, out, DMODEL, DFF);
        return;
    }

    // -------- fp32 fallbacks (round-2 proven paths) --------
    const size_t CE  = (size_t)SEQ * DFF;
    const size_t P32 = CE * sizeof(float);
    const size_t P16 = CE * sizeof(bf16raw);

    dim3 gu(DFF / BN, SEQ / BM);
    dim3 gdc(DMODEL / BN, SEQ / BM);
    const int nconv = SEQ * (DFF / 4) / 256;

    if (ws_size >= 3 * P32) {
        float* gpre = (float*)d_ws;
        float* upre = gpre + CE;
        float* hbuf = upre + CE;
        for (int b = 0; b < BATCH; ++b) {
            const float* xbp = x + (size_t)b * SEQ * DMODEL;
            float* outb = out + (size_t)b * SEQ * DMODEL;
            sgemm_bias_kernel<float, float><<<gu, blk, 0, stream>>>(xbp, Wg, bg, gpre, DFF, DMODEL);
            sgemm_bias_kernel<float, float><<<gu, blk, 0, stream>>>(xbp, Wu, bu, upre, DFF, DMODEL);
            conv_silu_mul_kernel<float, float><<<nconv * 2, blk, 0, stream>>>(
                gpre, upre, cgw, cgb, cuw, cub, hbuf);
            sgemm_bias_kernel<float, float><<<gdc, blk, 0, stream>>>(hbuf, Wd, bd, outb, DMODEL, DFF);
        }
    } else if (ws_size >= 3 * P16) {
        bf16raw* gpre = (bf16raw*)d_ws;
        bf16raw* upre = gpre + CE;
        bf16raw* hbuf = upre + CE;
        for (int b = 0; b < BATCH; ++b) {
            const float* xbp = x + (size_t)b * SEQ * DMODEL;
            float* outb = out + (size_t)b * SEQ * DMODEL;
            sgemm_bias_kernel<float, bf16raw><<<gu, blk, 0, stream>>>(xbp, Wg, bg, gpre, DFF, DMODEL);
            sgemm_bias_kernel<float, bf16raw><<<gu, blk, 0, stream>>>(xbp, Wu, bu, upre, DFF, DMODEL);
            conv_silu_mul_kernel<bf16raw, bf16raw><<<nconv * 2, blk, 0, stream>>>(
                gpre, upre, cgw, cgb, cuw, cub, hbuf);
            sgemm_bias_kernel<bf16raw, float><<<gdc, blk, 0, stream>>>(hbuf, Wd, bd, outb, DMODEL, DFF);
        }
    }
}

// Round 4
// 386.194 us; speedup vs baseline: 7.4949x; 1.1431x over previous
//
#include <hip/hip_runtime.h>
#include <hip/hip_bf16.h>
#include <cstdint>

#define BATCH  4
#define SEQ    2048
#define DMODEL 1024
#define DFF    4096
#define MTOT   (BATCH * SEQ)   // 8192
#define KCONV  5
#define PADC   2

using bf16raw = unsigned short;
typedef __attribute__((ext_vector_type(8))) short bf16x8;
typedef __attribute__((ext_vector_type(4))) float f32x4;

__device__ __forceinline__ float bf2f(bf16raw u) {
    return __uint_as_float(((uint32_t)u) << 16);
}
__device__ __forceinline__ bf16raw f2bf(float f) {
    uint32_t u = __float_as_uint(f);
    u = (u + 0x7fffu + ((u >> 16) & 1u)) >> 16;   // RNE
    return (bf16raw)u;
}

// ---------------- prep kernels ----------------

__global__ __launch_bounds__(256)
void cvt_bf16_kernel(const float* __restrict__ in, bf16raw* __restrict__ out, int n4)
{
    const int i = blockIdx.x * 256 + threadIdx.x;
    if (i >= n4) return;
    const float4 v = reinterpret_cast<const float4*>(in)[i];
    ushort4 o;
    o.x = f2bf(v.x); o.y = f2bf(v.y); o.z = f2bf(v.z); o.w = f2bf(v.w);
    reinterpret_cast<ushort4*>(out)[i] = o;
}

// out[C][R] = bf16(in[R][C]); R,C multiples of 32
__global__ __launch_bounds__(256)
void transpose_cvt_kernel(const float* __restrict__ in, bf16raw* __restrict__ out,
                          int R, int C)
{
    __shared__ float tile[32][33];
    const int r0 = blockIdx.y * 32, c0 = blockIdx.x * 32;
    const int tx = threadIdx.x & 31, ty = threadIdx.x >> 5;  // ty 0..7
#pragma unroll
    for (int i = 0; i < 4; ++i)
        tile[ty + i * 8][tx] = in[(size_t)(r0 + ty + i * 8) * C + c0 + tx];
    __syncthreads();
#pragma unroll
    for (int i = 0; i < 4; ++i)
        out[(size_t)(c0 + ty + i * 8) * R + r0 + tx] = f2bf(tile[tx][ty + i * 8]);
}

// conv weights [DFF][1][K] -> [K][DFF] fp32
__global__ __launch_bounds__(256)
void convw_reorder_kernel(const float* __restrict__ wg, const float* __restrict__ wu,
                          float* __restrict__ wgT, float* __restrict__ wuT)
{
    const int i = blockIdx.x * 256 + threadIdx.x;
    if (i >= KCONV * DFF) return;
    const int j = i / DFF, f = i - j * DFF;
    wgT[i] = wg[f * KCONV + j];
    wuT[i] = wu[f * KCONV + j];
}

// ---------------- 256x256 MFMA GEMM, BK=64, 8 waves, dbuf + counted vmcnt ----
// C[M][N] = A[M][K] @ BT[N][K]^T (+bias); M,N %256==0, K%(64*SPLITK)==0.
// LDS per K-tile: A[256][64] + B[256][64] bf16 = 64 KiB; x2 buffers = 128 KiB.
// Swizzle: within a 128B row (8 x 16B chunks), phys_chunk = logical ^ (row&7).
// Realized as pre-swizzled GLOBAL source + linear global_load_lds dest (rule #21),
// and swizzled ds_read addresses -> conflict-free fragment reads.

__device__ __forceinline__ void gll16(const bf16raw* g, const char* lds)
{
    __builtin_amdgcn_global_load_lds(
        (const __attribute__((address_space(1))) void*)g,
        (__attribute__((address_space(3))) void*)lds, 16, 0, 0);
}

template<typename CT, bool BIAS, int SPLITK>
__global__ __launch_bounds__(512, 2)
void gemm256_kernel(const bf16raw* __restrict__ A, const bf16raw* __restrict__ BT,
                    const float* __restrict__ bias0, const float* __restrict__ bias1,
                    CT* __restrict__ C, int M, int N, int K, int nbm, int nbn)
{
    __shared__ __align__(16) char smem[131072];   // 2 x (A 32K + B 32K)

    const int tid  = threadIdx.x;
    const int lane = tid & 63;
    const int wave = __builtin_amdgcn_readfirstlane(tid >> 6);
    const int wr = wave >> 2;          // 0..1 (M)
    const int wc = wave & 3;           // 0..3 (N)

    // ---- XCD-aware swizzle (grid is multiple of 8), column-major decompose ----
    const int nwg = nbm * nbn * SPLITK;
    const int cpx = nwg >> 3;
    const int bid = blockIdx.x;
    const int swz = (bid & 7) * cpx + (bid >> 3);
    int sk = 0, rem = swz;
    if constexpr (SPLITK > 1) { sk = swz / (nbm * nbn); rem = swz - sk * (nbm * nbn); }
    const int bx = rem / nbm;          // N-tile (slow) -> weights-stationary per XCD
    const int by = rem - bx * nbm;     // M-tile (fast)
    const int bm = by * 256;
    const int bn = bx * 256;

    const int klen = K / SPLITK;
    const int kbeg = sk * klen;
    const int NT   = klen / 64;
    CT* Cp = C + (size_t)sk * M * N;

    // ---- staging addresses (pre-swizzled global source, linear LDS dest) ----
    // thread covers chunk (inst*512 + tid); row = inst*64 + (tid>>3); phys k-chunk = tid&7
    // logical k-chunk at that slot = (tid&7) ^ (row&7) = (tid&7) ^ ((tid>>3)&7)
    const int srow = tid >> 3;                                   // 0..63
    const int kswz = (((tid & 7) ^ ((tid >> 3) & 7)) << 3);      // element offset 0..56
    const bf16raw* Asrc = A  + (size_t)(bm + srow) * K + kbeg + kswz;
    const bf16raw* Bsrc = BT + (size_t)(bn + srow) * K + kbeg + kswz;

    // ---- fragment-read offsets (bytes) within an A/B block ----
    // logical (row = R0 + (lane&15), kc = s*4 + (lane>>4)); row&7 == lane&7
    const int g4  = lane >> 4;
    const int r15 = lane & 15;
    const int key = lane & 7;
    const int off0 = r15 * 128 + (((0 + g4) ^ key) << 4);
    const int off1 = r15 * 128 + (((4 + g4) ^ key) << 4);

    f32x4 acc[8][4];
#pragma unroll
    for (int i = 0; i < 8; ++i)
#pragma unroll
        for (int j = 0; j < 4; ++j) acc[i][j] = (f32x4){0.f, 0.f, 0.f, 0.f};

    auto stage = [&](int t, int buf) {
        const bf16raw* Ag = Asrc + (size_t)t * 64;
        const bf16raw* Bg = Bsrc + (size_t)t * 64;
        const char* la = smem + buf * 65536 + tid * 16;
        const char* lb = la + 32768;
#pragma unroll
        for (int i = 0; i < 4; ++i) {
            gll16(Ag + (size_t)i * 64 * K, la + i * 8192);
            gll16(Bg + (size_t)i * 64 * K, lb + i * 8192);
        }
    };

    auto compute = [&](int buf) {
        const char* bufA = smem + buf * 65536 + wr * 16384;
        const char* bufB = smem + buf * 65536 + 32768 + wc * 8192;
        bf16x8 bfr[4][2];
#pragma unroll
        for (int nf = 0; nf < 4; ++nf) {
            bfr[nf][0] = *(const bf16x8*)(bufB + nf * 2048 + off0);
            bfr[nf][1] = *(const bf16x8*)(bufB + nf * 2048 + off1);
        }
#pragma unroll
        for (int q = 0; q < 4; ++q) {
            bf16x8 afr[2][2];
#pragma unroll
            for (int m2 = 0; m2 < 2; ++m2) {
                afr[m2][0] = *(const bf16x8*)(bufA + (q * 2 + m2) * 2048 + off0);
                afr[m2][1] = *(const bf16x8*)(bufA + (q * 2 + m2) * 2048 + off1);
            }
            __builtin_amdgcn_s_setprio(1);
#pragma unroll
            for (int m2 = 0; m2 < 2; ++m2)
#pragma unroll
                for (int nf = 0; nf < 4; ++nf) {
                    acc[q * 2 + m2][nf] = __builtin_amdgcn_mfma_f32_16x16x32_bf16(
                        afr[m2][0], bfr[nf][0], acc[q * 2 + m2][nf], 0, 0, 0);
                    acc[q * 2 + m2][nf] = __builtin_amdgcn_mfma_f32_16x16x32_bf16(
                        afr[m2][1], bfr[nf][1], acc[q * 2 + m2][nf], 0, 0, 0);
                }
            __builtin_amdgcn_s_setprio(0);
        }
    };

    stage(0, 0);
    for (int t = 0; t < NT; ++t) {
        const int cur = t & 1;
        if (t + 1 < NT) {
            stage(t + 1, cur ^ 1);
            // tile t landed iff outstanding <= t+1's 8 loads (per-wave queue proof)
            asm volatile("s_waitcnt vmcnt(8)" ::: "memory");
        } else {
            asm volatile("s_waitcnt vmcnt(0)" ::: "memory");
        }
        __builtin_amdgcn_s_barrier();        // all waves: tile t visible
        compute(cur);
        __builtin_amdgcn_s_barrier();        // all reads of buf[cur] done
        asm volatile("" ::: "memory");
    }

    // ---- epilogue: C/D layout col=lane&15, row=(lane>>4)*4+reg  [m89] ----
    const int er = g4 << 2;
#pragma unroll
    for (int nf = 0; nf < 4; ++nf) {
        const int nn = bn + wc * 64 + nf * 16 + r15;
        float bv = 0.f;
        if constexpr (BIAS) bv = (nn < DFF) ? bias0[nn] : bias1[nn - DFF];
#pragma unroll
        for (int mf = 0; mf < 8; ++mf) {
            const int mrow = bm + wr * 128 + mf * 16 + er;
#pragma unroll
            for (int j = 0; j < 4; ++j) {
                const float v = acc[mf][nf][j] + bv;
                if constexpr (sizeof(CT) == 2)
                    Cp[(size_t)(mrow + j) * N + nn] = f2bf(v);
                else
                    Cp[(size_t)(mrow + j) * N + nn] = v;
            }
        }
    }
}

// ---------------- split-K reduce + bias (fp32 partials -> fp32 out) --------
__global__ __launch_bounds__(256)
void reduce_bias_kernel(const float* __restrict__ part, const float* __restrict__ bd,
                        float* __restrict__ out)
{
    const int i = blockIdx.x * 256 + threadIdx.x;           // float4 index
    const int d = (i & (DMODEL / 4 - 1)) * 4;
    const float4 a = reinterpret_cast<const float4*>(part)[i];
    const float4 b = reinterpret_cast<const float4*>(part + (size_t)MTOT * DMODEL)[i];
    const float4 bb = *reinterpret_cast<const float4*>(bd + d);
    float4 o;
    o.x = a.x + b.x + bb.x; o.y = a.y + b.y + bb.y;
    o.z = a.z + b.z + bb.z; o.w = a.w + b.w + bb.w;
    reinterpret_cast<float4*>(out)[i] = o;
}

// ---------------- conv + silu + mul (bf16 in/out, src row stride S) --------
__global__ __launch_bounds__(256)
void conv_silu_mul_bf16_kernel(const bf16raw* __restrict__ gp, const bf16raw* __restrict__ up,
                               const float* __restrict__ wgT, const float* __restrict__ cbg,
                               const float* __restrict__ wuT, const float* __restrict__ cbu,
                               bf16raw* __restrict__ h, int S)
{
    const int idx = blockIdx.x * 256 + threadIdx.x;
    const int f   = (idx & (DFF / 8 - 1)) << 3;
    const int row = idx >> 9;
    const int l   = row & (SEQ - 1);
    const int rb  = row - l;                       // batch base row

    float g[8], u[8];
    {
        const float4 a0 = *reinterpret_cast<const float4*>(cbg + f);
        const float4 a1 = *reinterpret_cast<const float4*>(cbg + f + 4);
        const float4 b0 = *reinterpret_cast<const float4*>(cbu + f);
        const float4 b1 = *reinterpret_cast<const float4*>(cbu + f + 4);
        g[0]=a0.x; g[1]=a0.y; g[2]=a0.z; g[3]=a0.w; g[4]=a1.x; g[5]=a1.y; g[6]=a1.z; g[7]=a1.w;
        u[0]=b0.x; u[1]=b0.y; u[2]=b0.z; u[3]=b0.w; u[4]=b1.x; u[5]=b1.y; u[6]=b1.z; u[7]=b1.w;
    }

#pragma unroll
    for (int j = 0; j < KCONV; ++j) {
        const int ls = l + j - PADC;
        if (ls < 0 || ls >= SEQ) continue;          // per-batch zero padding
        const size_t off = (size_t)(rb + ls) * S + f;
        const bf16x8 gv = *reinterpret_cast<const bf16x8*>(gp + off);
        const bf16x8 uv = *reinterpret_cast<const bf16x8*>(up + off);
        const float4 wa0 = *reinterpret_cast<const float4*>(wgT + j * DFF + f);
        const float4 wa1 = *reinterpret_cast<const float4*>(wgT + j * DFF + f + 4);
        const float4 wb0 = *reinterpret_cast<const float4*>(wuT + j * DFF + f);
        const float4 wb1 = *reinterpret_cast<const float4*>(wuT + j * DFF + f + 4);
        const float wg8[8] = {wa0.x, wa0.y, wa0.z, wa0.w, wa1.x, wa1.y, wa1.z, wa1.w};
        const float wu8[8] = {wb0.x, wb0.y, wb0.z, wb0.w, wb1.x, wb1.y, wb1.z, wb1.w};
#pragma unroll
        for (int c = 0; c < 8; ++c) {
            g[c] += bf2f((bf16raw)gv[c]) * wg8[c];
            u[c] += bf2f((bf16raw)uv[c]) * wu8[c];
        }
    }

    bf16x8 hv;
#pragma unroll
    for (int c = 0; c < 8; ++c) {
        const float s = g[c] / (1.f + __expf(-g[c]));
        hv[c] = (short)f2bf(s * u[c]);
    }
    *reinterpret_cast<bf16x8*>(h + (size_t)row * DFF + f) = hv;
}

// ---------------- fp32 fallback kernels (round-2 proven) -------------------

#define BM 128
#define BN 128
#define BK 8

__device__ __forceinline__ void load4f(const float* p, float v[4]) {
    const float4 t = *reinterpret_cast<const float4*>(p);
    v[0] = t.x; v[1] = t.y; v[2] = t.z; v[3] = t.w;
}

__global__ __launch_bounds__(256)
void sgemm_bias_kernel(const float* __restrict__ A, const float* __restrict__ B,
                       const float* __restrict__ bias, float* __restrict__ C,
                       int N, int K)
{
    __shared__ float As[BK][BM];
    __shared__ float Bs[BK][BN];

    const int tid = threadIdx.x;
    const int bm  = blockIdx.y * BM;
    const int bn  = blockIdx.x * BN;
    const int tx  = tid & 15;
    const int ty  = tid >> 4;

    const int arow = tid >> 1;
    const int acol = (tid & 1) * 4;
    const int brow = tid >> 5;
    const int bcol = (tid & 31) * 4;

    const float* Ap = A + (size_t)(bm + arow) * K + acol;
    const float* Bp = B + (size_t)brow * N + bn + bcol;

    float acc[8][8];
#pragma unroll
    for (int i = 0; i < 8; ++i)
#pragma unroll
        for (int j = 0; j < 8; ++j) acc[i][j] = 0.f;

    for (int k0 = 0; k0 < K; k0 += BK) {
        float av[4];
        load4f(Ap + k0, av);
        const float4 bv = *reinterpret_cast<const float4*>(Bp + (size_t)k0 * N);
        __syncthreads();
#pragma unroll
        for (int i = 0; i < 4; ++i) As[acol + i][arow] = av[i];
        *reinterpret_cast<float4*>(&Bs[brow][bcol]) = bv;
        __syncthreads();
#pragma unroll
        for (int kk = 0; kk < BK; ++kk) {
            const float4 a0 = *reinterpret_cast<const float4*>(&As[kk][ty * 4]);
            const float4 a1 = *reinterpret_cast<const float4*>(&As[kk][64 + ty * 4]);
            const float4 b0 = *reinterpret_cast<const float4*>(&Bs[kk][tx * 4]);
            const float4 b1 = *reinterpret_cast<const float4*>(&Bs[kk][64 + tx * 4]);
            const float am[8] = {a0.x, a0.y, a0.z, a0.w, a1.x, a1.y, a1.z, a1.w};
            const float bb[8] = {b0.x, b0.y, b0.z, b0.w, b1.x, b1.y, b1.z, b1.w};
#pragma unroll
            for (int mi = 0; mi < 8; ++mi)
#pragma unroll
                for (int nj = 0; nj < 8; ++nj)
                    acc[mi][nj] += am[mi] * bb[nj];
        }
    }
#pragma unroll
    for (int mi = 0; mi < 8; ++mi) {
        const int m = bm + ((mi < 4) ? (ty * 4 + mi) : (64 + ty * 4 + (mi - 4)));
#pragma unroll
        for (int g = 0; g < 2; ++g) {
            const int n = bn + g * 64 + tx * 4;
            float4 o;
            o.x = acc[mi][g * 4 + 0] + bias[n + 0];
            o.y = acc[mi][g * 4 + 1] + bias[n + 1];
            o.z = acc[mi][g * 4 + 2] + bias[n + 2];
            o.w = acc[mi][g * 4 + 3] + bias[n + 3];
            *reinterpret_cast<float4*>(&C[(size_t)m * N + n]) = o;
        }
    }
}

__global__ __launch_bounds__(256)
void conv_silu_mul_f32_kernel(const float* __restrict__ gp, const float* __restrict__ up,
                              const float* __restrict__ wg, const float* __restrict__ cbg,
                              const float* __restrict__ wu, const float* __restrict__ cbu,
                              float* __restrict__ hout)
{
    const int idx = blockIdx.x * 256 + threadIdx.x;
    const int f   = (idx & (DFF / 4 - 1)) * 4;
    const int l   = idx >> 10;

    float g[4], u[4];
    load4f(cbg + f, g);
    load4f(cbu + f, u);
#pragma unroll
    for (int j = 0; j < KCONV; ++j) {
        const int ls = l + j - PADC;
        if (ls < 0 || ls >= SEQ) continue;
        const size_t off = (size_t)ls * DFF + f;
        float gv[4], uv[4];
        load4f(gp + off, gv);
        load4f(up + off, uv);
#pragma unroll
        for (int c = 0; c < 4; ++c) {
            g[c] += gv[c] * wg[(f + c) * KCONV + j];
            u[c] += uv[c] * wu[(f + c) * KCONV + j];
        }
    }
    float h[4];
#pragma unroll
    for (int c = 0; c < 4; ++c) {
        const float s = g[c] / (1.f + __expf(-g[c]));
        h[c] = s * u[c];
    }
    float4 o; o.x = h[0]; o.y = h[1]; o.z = h[2]; o.w = h[3];
    *reinterpret_cast<float4*>(&hout[(size_t)l * DFF + f]) = o;
}

// ---------------- launch ----------------

extern "C" void kernel_launch(void* const* d_in, const int* in_sizes, int n_in,
                              void* d_out, int out_size, void* d_ws, size_t ws_size,
                              hipStream_t stream)
{
    const float* x   = (const float*)d_in[0];
    const float* Wg  = (const float*)d_in[1];
    const float* bg  = (const float*)d_in[2];
    const float* Wu  = (const float*)d_in[3];
    const float* bu  = (const float*)d_in[4];
    const float* cgw = (const float*)d_in[5];
    const float* cgb = (const float*)d_in[6];
    const float* cuw = (const float*)d_in[7];
    const float* cub = (const float*)d_in[8];
    const float* Wd  = (const float*)d_in[9];
    const float* bd  = (const float*)d_in[10];
    float* out = (float*)d_out;

    const dim3 blk(256);
    auto align256 = [](size_t v) { return (v + 255) & ~(size_t)255; };

    // ws layout (MFMA path): ~232 MiB total (empirically ws >= 281 MiB)
    const size_t SZ_XB  = (size_t)MTOT * DMODEL * 2;        // 16 MiB
    const size_t SZ_WGU = (size_t)2 * DFF * DMODEL * 2;     // 16 MiB (Wg^T | Wu^T)
    const size_t SZ_WD  = (size_t)DMODEL * DFF * 2;         //  8 MiB
    const size_t SZ_CW  = (size_t)KCONV * DFF * 4;          // 80 KiB each
    const size_t SZ_H   = (size_t)MTOT * DFF * 2;           // 64 MiB
    const size_t SZ_UP  = (size_t)MTOT * 2 * DFF * 2;       // 128 MiB  [8192][8192] bf16
    // split-K partials (64 MiB fp32) overlay SZ_UP region (consumed by conv first)

    size_t cur = 0;
    const size_t oXB  = cur; cur = align256(cur + SZ_XB);
    const size_t oWGU = cur; cur = align256(cur + SZ_WGU);
    const size_t oWD  = cur; cur = align256(cur + SZ_WD);
    const size_t oCWg = cur; cur = align256(cur + SZ_CW);
    const size_t oCWu = cur; cur = align256(cur + SZ_CW);
    const size_t oH   = cur; cur = align256(cur + SZ_H);
    const size_t oUP  = cur; cur = align256(cur + SZ_UP);
    const size_t need = cur;

    if (ws_size >= need) {
        bf16raw* xb   = (bf16raw*)((char*)d_ws + oXB);
        bf16raw* Wgu  = (bf16raw*)((char*)d_ws + oWGU);
        bf16raw* WdT  = (bf16raw*)((char*)d_ws + oWD);
        float*   cwg  = (float*)((char*)d_ws + oCWg);
        float*   cwu  = (float*)((char*)d_ws + oCWu);
        bf16raw* h    = (bf16raw*)((char*)d_ws + oH);
        bf16raw* Cup  = (bf16raw*)((char*)d_ws + oUP);
        float*   part = (float*)((char*)d_ws + oUP);        // overlay

        // prep
        cvt_bf16_kernel<<<(MTOT * DMODEL / 4 + 255) / 256, blk, 0, stream>>>(x, xb, MTOT * DMODEL / 4);
        transpose_cvt_kernel<<<dim3(DFF / 32, DMODEL / 32), blk, 0, stream>>>(Wg, Wgu, DMODEL, DFF);
        transpose_cvt_kernel<<<dim3(DFF / 32, DMODEL / 32), blk, 0, stream>>>(Wu, Wgu + (size_t)DFF * DMODEL, DMODEL, DFF);
        transpose_cvt_kernel<<<dim3(DMODEL / 32, DFF / 32), blk, 0, stream>>>(Wd, WdT, DFF, DMODEL);
        convw_reorder_kernel<<<(KCONV * DFF + 255) / 256, blk, 0, stream>>>(cgw, cuw, cwg, cwu);

        // fused up-GEMM: [8192,1024] @ [1024,8192(=Wg|Wu)] -> Cup [8192][8192] bf16
        {
            const int nbm = MTOT / 256, nbn = (2 * DFF) / 256;   // 32 x 32
            gemm256_kernel<bf16raw, true, 1><<<nbm * nbn, dim3(512), 0, stream>>>(
                xb, Wgu, bg, bu, Cup, MTOT, 2 * DFF, DMODEL, nbm, nbn);
        }

        // conv + silu + mul: Cup(gate cols 0..4095, up cols 4096..8191) -> h bf16
        conv_silu_mul_bf16_kernel<<<MTOT * (DFF / 8) / 256, blk, 0, stream>>>(
            Cup, Cup + DFF, cwg, cgb, cwu, cub, h, 2 * DFF);

        // down-GEMM split-K=2: h [8192,4096] @ WdT^T -> partials fp32, then reduce+bias
        {
            const int nbm = MTOT / 256, nbn = DMODEL / 256;      // 32 x 4, x2 sk = 256 wg
            gemm256_kernel<float, false, 2><<<nbm * nbn * 2, dim3(512), 0, stream>>>(
                h, WdT, nullptr, nullptr, part, MTOT, DMODEL, DFF, nbm, nbn);
        }
        reduce_bias_kernel<<<MTOT * DMODEL / 4 / 256, blk, 0, stream>>>(part, bd, out);
        return;
    }

    // -------- fp32 per-batch fallback (round-2 proven) --------
    const size_t CE  = (size_t)SEQ * DFF;
    const size_t P32 = CE * sizeof(float);
    if (ws_size < 3 * P32) return;   // diagnostic: clean absmax failure

    float* gpre = (float*)d_ws;
    float* upre = gpre + CE;
    float* hbuf = upre + CE;
    dim3 gu(DFF / BN, SEQ / BM);
    dim3 gdc(DMODEL / BN, SEQ / BM);
    const int nconv = SEQ * (DFF / 4) / 256;
    for (int b = 0; b < BATCH; ++b) {
        const float* xbp = x + (size_t)b * SEQ * DMODEL;
        float* outb = out + (size_t)b * SEQ * DMODEL;
        sgemm_bias_kernel<<<gu, blk, 0, stream>>>(xbp, Wg, bg, gpre, DFF, DMODEL);
        sgemm_bias_kernel<<<gu, blk, 0, stream>>>(xbp, Wu, bu, upre, DFF, DMODEL);
        conv_silu_mul_f32_kernel<<<nconv, blk, 0, stream>>>(gpre, upre, cgw, cgb, cuw, cub, hbuf);
        sgemm_bias_kernel<<<gdc, blk, 0, stream>>>(hbuf, Wd, bd, outb, DMODEL, DFF);
    }
}